// Round 16
// baseline (132.467 us; speedup 1.0000x reference)
//
#include <hip/hip_runtime.h>
#include <hip/hip_bf16.h>

// Problem: B=2, S=2048, E=1024, H=16, D=64. All inputs fp32, output fp32.
// Pipeline: prep (cvt X->bf16 + wtrans W->bf16 [N][K], one launch)
//           | fused QKV GEMM (1D XCD-chunked, BN=128, 2-phase prefetch)
//           -> Q(scaled log2e/8),K [BH][S][D], V^T [BH][D][S_perm]
//           | flash attention (KVBLK=128, 4 waves x 32q = 128q/block,
//           32x32x16 MFMA, gload_lds prefetch dbuf + 1 full-drain
//           barrier/tile, in-lane softmax + max3 tree, ONE shfl_xor(32)/tile,
//           lane-local lrow merged in epilogue, defer-max T13, P in-register,
//           setprio T5) | GEMM BN=64 (XCD-chunked) -> fp32 + bo.
// LDS tiles: T2 XOR swizzle byte ^= ((row&7)<<4) within each row; staged via
// global_load_lds with inverse-swizzled global source (linear LDS dest).
// History: r3 dbuf+counted-vmcnt raced -> full-drain barriers only.
//          r7 zero-staging attn latency-bound -> LDS staging mandatory.
//          r8 AF32 cvt-fusion regressed -> separate cvt pass.
//          r11 permlane32_swap self-swap reduce FAILED -> shfl_xor merges.
//          r13 split-K=2 REGRESSED (LDS-capped occupancy) -> reverted.
//          r14 GEMM 2-phase prefetch: 138.8->133.5. r15 prep-merge + T1
//          XCD-chunk: 133.5->124.1.
//          r16: attn KVBLK 64->128, 4-wave/128q blocks (param change within
//          verified template): tiles 32->16, staging shared 4-way, grid 512
//          = exactly 2 blocks/CU (no tail), 8 waves/CU preserved.

#define EMBED 1024
#define NHEAD 16
#define HDIM 64
#define SEQ 2048
#define MROWS 4096  // B*S

typedef __attribute__((ext_vector_type(8))) __bf16 bf16x8;
typedef __attribute__((ext_vector_type(4))) float f32x4;
typedef __attribute__((ext_vector_type(16))) float f32x16;

__device__ __forceinline__ unsigned short f2bf(float f) {
  unsigned int u = __builtin_bit_cast(unsigned int, f);
  u += 0x7fffu + ((u >> 16) & 1u);  // round-to-nearest-even
  return (unsigned short)(u >> 16);
}

// packed f32x2 -> bf16x2 (T12 recipe; no builtin on gfx950)
__device__ __forceinline__ int cvtpk_bf16(float lo, float hi) {
  int r;
  asm("v_cvt_pk_bf16_f32 %0, %1, %2" : "=v"(r) : "v"(lo), "v"(hi));
  return r;
}

__device__ __forceinline__ float max3f(float a, float b, float c) {
  return fmaxf(fmaxf(a, b), c);  // clang fuses to v_max3_f32
}

// swizzled byte offset within a [rows][128B] LDS tile
__device__ __forceinline__ int swz(int row, int bcol) {
  return row * 128 + (bcol ^ ((row & 7) << 4));
}
// swizzled byte offset within a [rows][256B] LDS tile (attn V)
__device__ __forceinline__ int swzv(int row, int bcol) {
  return row * 256 + (bcol ^ ((row & 7) << 4));
}

// async global->LDS, 16B per lane. LDS dest = base + lane*16 (linear).
__device__ __forceinline__ void gload16(const void* g, void* l) {
  __builtin_amdgcn_global_load_lds((const __attribute__((address_space(1))) void*)g,
                                   (__attribute__((address_space(3))) void*)l, 16, 0, 0);
}

// ---- prep: blocks 0..6143 = fp32->bf16 cvt of q/k/v (8 elts/thread);
//            blocks 6144..7167 = W [K][N] fp32 -> Wt [N][K] bf16 transpose.
__global__ __launch_bounds__(256) void prep(const float* __restrict__ q32, const float* __restrict__ k32,
                                            const float* __restrict__ v32,
                                            unsigned short* __restrict__ Xq, unsigned short* __restrict__ Xk,
                                            unsigned short* __restrict__ Xv,
                                            const float* __restrict__ w0, const float* __restrict__ w1,
                                            const float* __restrict__ w2, const float* __restrict__ w3,
                                            unsigned short* __restrict__ o0, unsigned short* __restrict__ o1,
                                            unsigned short* __restrict__ o2, unsigned short* __restrict__ o3) {
  __shared__ float tile[64][65];  // used by wtrans branch only
  const int id = blockIdx.x;
  if (id < 6144) {
    const float* in; unsigned short* out;
    switch (id >> 11) {
      case 0: in = q32; out = Xq; break;
      case 1: in = k32; out = Xk; break;
      default: in = v32; out = Xv; break;
    }
    int i = (id & 2047) * 256 + threadIdx.x;
    const float4* p = reinterpret_cast<const float4*>(in) + (size_t)i * 2;
    float4 a = p[0], b = p[1];
    int4 r;
    r.x = cvtpk_bf16(a.x, a.y);
    r.y = cvtpk_bf16(a.z, a.w);
    r.z = cvtpk_bf16(b.x, b.y);
    r.w = cvtpk_bf16(b.z, b.w);
    reinterpret_cast<int4*>(out)[i] = r;
  } else {
    const int wid = id - 6144;
    const float* src; unsigned short* dst;
    switch (wid >> 8) {
      case 0: src = w0; dst = o0; break;
      case 1: src = w1; dst = o1; break;
      case 2: src = w2; dst = o2; break;
      default: src = w3; dst = o3; break;
    }
    const int k0 = ((wid >> 4) & 15) * 64, n0 = (wid & 15) * 64;
    const int c = threadIdx.x & 63, r0 = threadIdx.x >> 6;
#pragma unroll
    for (int i = 0; i < 16; ++i) {
      int r = r0 + i * 4;
      tile[r][c] = src[(size_t)(k0 + r) * EMBED + n0 + c];
    }
    __syncthreads();
#pragma unroll
    for (int i = 0; i < 16; ++i) {
      int nr = r0 + i * 4;
      dst[(size_t)(n0 + nr) * EMBED + k0 + c] = f2bf(tile[c][nr]);
    }
  }
}

// ---- shared GEMM core: C[128 x BN tile at (m0,n0)] = A @ Bt^T + bias ----
// A bf16 [M][K]; Bt bf16 [N][K]. Staging via global_load_lds (m97 pattern),
// 2-phase prefetch (r14-verified): {drain-barrier; ds_read ALL frags -> regs;
// read-barrier; gload(next) into same buffer; MFMA}.
// BN=128: waves 2x2, acc[4][4].  BN=64: waves 4x1, acc[2][4].
// mode 0: bf16 scatter to [B*H][S][D]; mode 1: fp32 row-major;
// mode 2: bf16 V^T scatter to [B*H][D][S] with seq-quartet bit-swap
//         (s-quartet q -> position-quartet ((q&1)<<1)|(q>>1)) so attn's PV
//         in-lane A-fragment permutation is compensated in V's layout.
template <int BN>
__device__ __forceinline__ void gemm_core(const unsigned short* __restrict__ A,
                                          const unsigned short* __restrict__ Bt,
                                          const float* __restrict__ bias,
                                          void* __restrict__ C, float oscale, int mode,
                                          int m0, int n0) {
  constexpr int K = EMBED;
  constexpr int MF = (BN == 128) ? 4 : 2;     // 16-row fragments per wave (M)
  constexpr int BRW = BN / 4;                 // B rows staged per wave
  __shared__ __align__(16) unsigned short Alds[128 * 64];
  __shared__ __align__(16) unsigned short Blds[BN * 64];
  char* Ab8 = (char*)Alds; char* Bb8 = (char*)Blds;
  const char* AB = (const char*)A;
  const char* BB = (const char*)Bt;
  const int tid = threadIdx.x;
  const int lane = tid & 63, w = tid >> 6;
  const int wr = (BN == 128) ? (w >> 1) : w;
  const int wc = (BN == 128) ? (w & 1) : 0;
  const int fr = lane & 15, fq = lane >> 4;
  const int bcol = (lane & 7) * 16;
  const int gsc = bcol ^ ((lane >> 3) << 4);  // row&7 == lane>>3 for all staged rows

  f32x4 acc[MF][4];
#pragma unroll
  for (int m = 0; m < MF; ++m)
#pragma unroll
    for (int n = 0; n < 4; ++n) acc[m][n] = f32x4{0.f, 0.f, 0.f, 0.f};

#define GSTAGE(k0_)                                                                          \
  {                                                                                          \
    _Pragma("unroll") for (int i_ = 0; i_ < 4; ++i_) {                                       \
      int row_ = w * 32 + i_ * 8 + (lane >> 3);                                              \
      gload16(AB + (size_t)(m0 + row_) * (K * 2) + (k0_)*2 + gsc, Ab8 + w * 4096 + i_ * 1024); \
    }                                                                                        \
    _Pragma("unroll") for (int i_ = 0; i_ < BRW / 8; ++i_) {                                 \
      int row_ = w * BRW + i_ * 8 + (lane >> 3);                                             \
      gload16(BB + (size_t)(n0 + row_) * (K * 2) + (k0_)*2 + gsc,                            \
              Bb8 + w * (BRW * 128) + i_ * 1024);                                            \
    }                                                                                        \
  }

  GSTAGE(0);  // prologue

  for (int k0 = 0; k0 < K; k0 += 64) {
    __syncthreads();  // drains vmcnt(0): tile k0 fully staged
    // ds_read ALL fragments of tile k0 into registers
    bf16x8 af2[2][MF], bf2[2][4];
#pragma unroll
    for (int ks = 0; ks < 2; ++ks) {
#pragma unroll
      for (int m = 0; m < MF; ++m) {
        int ar = wr * (MF * 16) + m * 16 + fr;
        af2[ks][m] = *reinterpret_cast<const bf16x8*>(Ab8 + swz(ar, ks * 64 + fq * 16));
      }
#pragma unroll
      for (int n = 0; n < 4; ++n) {
        int br = wc * 64 + n * 16 + fr;
        bf2[ks][n] = *reinterpret_cast<const bf16x8*>(Bb8 + swz(br, ks * 64 + fq * 16));
      }
    }
    __syncthreads();  // all waves done reading -> buffer free for prefetch
    if (k0 + 64 < K) GSTAGE(k0 + 64);  // async prefetch; hides under MFMA
#pragma unroll
    for (int ks = 0; ks < 2; ++ks)
#pragma unroll
      for (int m = 0; m < MF; ++m)
#pragma unroll
        for (int n = 0; n < 4; ++n)
          acc[m][n] = __builtin_amdgcn_mfma_f32_16x16x32_bf16(af2[ks][m], bf2[ks][n], acc[m][n], 0, 0, 0);
  }
#undef GSTAGE

#pragma unroll
  for (int n = 0; n < 4; ++n) {
    int col = n0 + wc * 64 + n * 16 + fr;
    float bv = bias[col];
#pragma unroll
    for (int m = 0; m < MF; ++m) {
      int rowb = m0 + wr * (MF * 16) + m * 16 + fq * 4;
      if (mode == 2) {
        int b = rowb >> 11, s0 = rowb & (SEQ - 1);
        // seq-quartet bit-swap: quartet q -> ((q&1)<<1)|(q>>1) within each 16
        int s0p = (s0 & ~12) | ((s0 & 4) << 1) | ((s0 & 8) >> 1);
        int h = col >> 6, d = col & 63;
        int2 pk;
        pk.x = cvtpk_bf16((acc[m][n][0] + bv) * oscale, (acc[m][n][1] + bv) * oscale);
        pk.y = cvtpk_bf16((acc[m][n][2] + bv) * oscale, (acc[m][n][3] + bv) * oscale);
        *reinterpret_cast<int2*>(
            &reinterpret_cast<unsigned short*>(C)[((size_t)((b * NHEAD + h) * HDIM + d)) * SEQ + s0p]) = pk;
      } else if (mode == 0) {
#pragma unroll
        for (int r = 0; r < 4; ++r) {
          int row = rowb + r;
          float v = (acc[m][n][r] + bv) * oscale;
          int b = row >> 11, s = row & (SEQ - 1), h = col >> 6, d = col & 63;
          reinterpret_cast<unsigned short*>(C)[((size_t)((b * NHEAD + h) * SEQ + s) << 6) + d] = f2bf(v);
        }
      } else {
#pragma unroll
        for (int r = 0; r < 4; ++r)
          reinterpret_cast<float*>(C)[(size_t)(rowb + r) * EMBED + col] = acc[m][n][r] + bv;
      }
    }
  }
}

// fused QKV projection, 1D grid of 768 with XCD-chunked swizzle.
__global__ __launch_bounds__(256) void gemm_qkv(
    const unsigned short* __restrict__ Xq, const unsigned short* __restrict__ Xk,
    const unsigned short* __restrict__ Xv,
    const unsigned short* __restrict__ Wqt, const unsigned short* __restrict__ Wkt,
    const unsigned short* __restrict__ Wvt,
    const float* __restrict__ bq, const float* __restrict__ bk, const float* __restrict__ bv,
    unsigned short* __restrict__ Qb, unsigned short* __restrict__ Kb,
    unsigned short* __restrict__ Vtb, float qscale) {
  const int id = blockIdx.x;
  const int lg = (id & 7) * 96 + (id >> 3);  // bijective: 768 = 8*96
  const int z = lg >> 8, rem = lg & 255;
  const int m0 = (rem >> 3) * 128, n0 = (rem & 7) * 128;
  switch (z) {
    case 0: gemm_core<128>(Xq, Wqt, bq, Qb, qscale, 0, m0, n0); break;
    case 1: gemm_core<128>(Xk, Wkt, bk, Kb, 1.0f, 0, m0, n0); break;
    default: gemm_core<128>(Xv, Wvt, bv, Vtb, 1.0f, 2, m0, n0); break;
  }
}

// output GEMM: 128x64 tiles, 1D grid of 512, XCD-chunked.
__global__ __launch_bounds__(256) void gemm_out(const unsigned short* __restrict__ A,
                                                const unsigned short* __restrict__ Bt,
                                                const float* __restrict__ bias,
                                                float* __restrict__ C) {
  const int id = blockIdx.x;
  const int lg = (id & 7) * 64 + (id >> 3);  // bijective: 512 = 8*64
  const int m0 = (lg >> 4) * 128, n0 = (lg & 15) * 64;
  gemm_core<64>(A, Bt, bias, C, 1.0f, 1, m0, n0);
}

// ---- flash attention, 32x32x16 MFMA, KVBLK=128, 4 waves x 32q ----
// Q,K bf16 [B*H][S][D] (Q pre-scaled by log2e/8); Vt bf16 [B*H][D][S_perm].
// Grid 512 = 16 q-blocks x 32 heads; 128 q/block; exactly 2 blocks/CU.
// Lane: ql=lane&31 (q), t=lane>>5. Per tile (128 keys): 16 QK MFMA (4 kb of
// 32 keys) + softmax + 16 PV MFMA. sc[kb] C-layout: col q=ql, row
// k=(reg&3)+8*(reg>>2)+4t within kb*32. [guide-verified]
// PA slot s in 0..7: pa = sc[s>>1] regs 8*(s&1)..+7; V^T's quartet-swapped
// seq layout compensates (mod-16-local, composes with any KVBLK).
// K tile [128 keys][128B d]; V tile [64 d][256B keys] (swzv).
// Sync template unchanged from r9/r12-verified: STAGE(kt+1) at top, ONE
// full-drain __syncthreads at tile end.
__global__ __launch_bounds__(256) void attn(const unsigned short* __restrict__ Q,
                                            const unsigned short* __restrict__ Kk,
                                            const unsigned short* __restrict__ Vt,
                                            unsigned short* __restrict__ AO) {
  __shared__ __align__(16) unsigned short Klds[2][128 * 64];  // 16KB each
  __shared__ __align__(16) unsigned short Vlds[2][64 * 128];  // 16KB each
  const int tid = threadIdx.x, lane = tid & 63, w = tid >> 6;  // w in {0..3}
  const int ql = lane & 31, t = lane >> 5;

  // XCD swizzle: 4 heads per XCD (round-robin lin%8), all q-blocks of those.
  const int lin = blockIdx.x;  // 0..511
  const int head = (lin & 7) * 4 + ((lin >> 3) & 3);
  const int q0 = (lin >> 5) * 128;
  const size_t hb = (size_t)head * SEQ * HDIM;
  const unsigned short* Qh = Q + hb;
  const char* KhB = (const char*)(Kk + hb);
  const char* VhB = (const char*)(Vt + hb);  // rows d, 4096B each

  // staging addressing (both-sides swizzle, rule #21):
  // K rows: krow&7 == lane>>3 (w*8, i*32 are mult of 8) -> gsc as GEMM.
  // V rows: vrow&7 == (w&1)*4 + (lane>>4) -> gscv; both loop-invariant.
  const int gsc = ((lane & 7) * 16) ^ ((lane >> 3) << 4);
  const int gscv = ((lane & 15) * 16) ^ ((((w & 1) << 2) + (lane >> 4)) << 4);

#define STAGE(kt_, b_)                                                                       \
  {                                                                                          \
    char* kb_ = (char*)Klds[b_];                                                             \
    char* vb_ = (char*)Vlds[b_];                                                             \
    _Pragma("unroll") for (int i_ = 0; i_ < 4; ++i_) {                                       \
      int krow_ = i_ * 32 + w * 8 + (lane >> 3);                                             \
      gload16(KhB + (size_t)((kt_)*128 + krow_) * 128 + gsc, kb_ + i_ * 4096 + tid * 16);    \
      int vrow_ = i_ * 16 + w * 4 + (lane >> 4);                                             \
      gload16(VhB + (size_t)vrow_ * (SEQ * 2) + (kt_)*256 + gscv,                            \
              vb_ + i_ * 4096 + tid * 16);                                                   \
    }                                                                                        \
  }

  // Q fragments (B-operand): lane supplies Q[ql][d = s*16 + t*8 + e]
  bf16x8 qf[4];
  {
    const unsigned short* qp = Qh + (size_t)(q0 + w * 32 + ql) * HDIM + t * 8;
    qf[0] = *reinterpret_cast<const bf16x8*>(qp);
    qf[1] = *reinterpret_cast<const bf16x8*>(qp + 16);
    qf[2] = *reinterpret_cast<const bf16x8*>(qp + 32);
    qf[3] = *reinterpret_cast<const bf16x8*>(qp + 48);
  }
  f32x16 oacc0 = {}, oacc1 = {};  // d-blocks 0..31, 32..63
  float mrow = -1e30f, lrow = 0.f;  // lrow LANE-LOCAL (half-sum); merged at end

  STAGE(0, 0);
  __syncthreads();  // drains vmcnt(0) -> tile 0 staged

  for (int kt = 0; kt < SEQ / 128; ++kt) {
    const int cur = kt & 1;
    const bool more = (kt + 1 < SEQ / 128);
    if (more) STAGE(kt + 1, cur ^ 1);  // async prefetch; drained by tile-end barrier
    char* Kb8 = (char*)Klds[cur];
    char* Vb8 = (char*)Vlds[cur];

    // S^T = K.Q^T (log2 domain): sc[kb] = keys kb*32..+32
    f32x16 sc[4] = {{}, {}, {}, {}};
    __builtin_amdgcn_s_setprio(1);
#pragma unroll
    for (int s = 0; s < 4; ++s) {
#pragma unroll
      for (int kb = 0; kb < 4; ++kb) {
        bf16x8 kf = *reinterpret_cast<const bf16x8*>(Kb8 + swz(kb * 32 + ql, s * 32 + t * 16));
        sc[kb] = __builtin_amdgcn_mfma_f32_32x32x16_bf16(kf, qf[s], sc[kb], 0, 0, 0);
      }
    }
    __builtin_amdgcn_s_setprio(0);

    // in-lane max over 64 scores (max3 trees), cross-half via verified shfl_xor
    float mkb[4];
#pragma unroll
    for (int kb = 0; kb < 4; ++kb) {
      float a = max3f(sc[kb][0], sc[kb][1], sc[kb][2]);
      float b = max3f(sc[kb][3], sc[kb][4], sc[kb][5]);
      float c = max3f(sc[kb][6], sc[kb][7], sc[kb][8]);
      float d = max3f(sc[kb][9], sc[kb][10], sc[kb][11]);
      float e = max3f(sc[kb][12], sc[kb][13], sc[kb][14]);
      mkb[kb] = fmaxf(max3f(max3f(a, b, c), d, e), sc[kb][15]);
    }
    float mt = fmaxf(fmaxf(mkb[0], mkb[1]), fmaxf(mkb[2], mkb[3]));
    mt = fmaxf(mt, __shfl_xor(mt, 32));

    // T13 defer-max: only rescale when some row's max grew past 2^8 headroom
    if (!__all(mt <= mrow + 8.0f)) {
      float mn = fmaxf(mrow, mt);
      float resc = __builtin_amdgcn_exp2f(mrow - mn);
      lrow *= resc;
#pragma unroll
      for (int r = 0; r < 16; ++r) {
        float rq = __shfl(resc, (r & 3) + 8 * (r >> 2) + 4 * t, 64);
        oacc0[r] *= rq;
        oacc1[r] *= rq;
      }
      mrow = mn;
    }

    // P = exp2(S - mrow) in place; lane-local partial sums (no per-tile merge)
#pragma unroll
    for (int kb = 0; kb < 4; ++kb)
#pragma unroll
      for (int i = 0; i < 16; ++i)
        sc[kb][i] = __builtin_amdgcn_exp2f(sc[kb][i] - mrow);
    float ps0 = 0.f, ps1 = 0.f, ps2 = 0.f, ps3 = 0.f;
#pragma unroll
    for (int i = 0; i < 8; ++i) {
      ps0 += sc[0][2 * i] + sc[0][2 * i + 1];
      ps1 += sc[1][2 * i] + sc[1][2 * i + 1];
      ps2 += sc[2][2 * i] + sc[2][2 * i + 1];
      ps3 += sc[3][2 * i] + sc[3][2 * i + 1];
    }
    lrow += (ps0 + ps1) + (ps2 + ps3);

    // PV: O[q][d] += P.V; PA slot s: pa = sc[s>>1] regs 8*(s&1)..+7 (in-lane;
    // quartet permutation baked into V^T's global layout). V-fragment rows d.
    __builtin_amdgcn_s_setprio(1);
#pragma unroll
    for (int s = 0; s < 8; ++s) {
      const int kb = s >> 1, base = 8 * (s & 1);
      int4 pw;
      pw.x = cvtpk_bf16(sc[kb][base + 0], sc[kb][base + 1]);
      pw.y = cvtpk_bf16(sc[kb][base + 2], sc[kb][base + 3]);
      pw.z = cvtpk_bf16(sc[kb][base + 4], sc[kb][base + 5]);
      pw.w = cvtpk_bf16(sc[kb][base + 6], sc[kb][base + 7]);
      bf16x8 pa = __builtin_bit_cast(bf16x8, pw);
      bf16x8 v0 = *reinterpret_cast<const bf16x8*>(Vb8 + swzv(ql, s * 32 + t * 16));
      bf16x8 v1 = *reinterpret_cast<const bf16x8*>(Vb8 + swzv(32 + ql, s * 32 + t * 16));
      oacc0 = __builtin_amdgcn_mfma_f32_32x32x16_bf16(pa, v0, oacc0, 0, 0, 0);
      oacc1 = __builtin_amdgcn_mfma_f32_32x32x16_bf16(pa, v1, oacc1, 0, 0, 0);
    }
    __builtin_amdgcn_s_setprio(0);

    __syncthreads();  // all waves done reading cur + prefetch drained (vmcnt 0)
  }
#undef STAGE

  // merge the two half-sums of lrow once
  lrow += __shfl_xor(lrow, 32);

  const int b = head >> 4, hh = head & 15;
#pragma unroll
  for (int r = 0; r < 16; ++r) {
    int qr = (r & 3) + 8 * (r >> 2) + 4 * t;
    float inv = 1.0f / __shfl(lrow, qr, 64);
    int srow = q0 + w * 32 + qr;
    size_t ob = (size_t)(b * SEQ + srow) * EMBED + hh * 64 + ql;
    AO[ob] = f2bf(oacc0[r] * inv);
    AO[ob + 32] = f2bf(oacc1[r] * inv);
  }
}

extern "C" void kernel_launch(void* const* d_in, const int* in_sizes, int n_in,
                              void* d_out, int out_size, void* d_ws, size_t ws_size,
                              hipStream_t stream) {
  const float* q32 = (const float*)d_in[0];
  const float* k32 = (const float*)d_in[1];
  const float* v32 = (const float*)d_in[2];
  const float* Wq = (const float*)d_in[3]; const float* bq = (const float*)d_in[4];
  const float* Wk = (const float*)d_in[5]; const float* bk = (const float*)d_in[6];
  const float* Wv = (const float*)d_in[7]; const float* bv = (const float*)d_in[8];
  const float* Wo = (const float*)d_in[9]; const float* bo = (const float*)d_in[10];
  float* out = (float*)d_out;

  char* ws = (char*)d_ws;
  const size_t MB = 1u << 20;
  unsigned short* Xq  = (unsigned short*)(ws + 0 * MB);
  unsigned short* Xk  = (unsigned short*)(ws + 8 * MB);
  unsigned short* Xv  = (unsigned short*)(ws + 16 * MB);
  unsigned short* Wqt = (unsigned short*)(ws + 24 * MB);
  unsigned short* Wkt = (unsigned short*)(ws + 26 * MB);
  unsigned short* Wvt = (unsigned short*)(ws + 28 * MB);
  unsigned short* Wot = (unsigned short*)(ws + 30 * MB);
  unsigned short* Qb  = (unsigned short*)(ws + 32 * MB);
  unsigned short* Kb  = (unsigned short*)(ws + 40 * MB);
  unsigned short* Vtb = (unsigned short*)(ws + 48 * MB);
  unsigned short* AO  = Xq;  // safe: GEMM-Q (sole Xq reader) completes before attn writes

  prep<<<7168, 256, 0, stream>>>(q32, k32, v32, Xq, Xk, Xv,
                                 Wq, Wk, Wv, Wo, Wqt, Wkt, Wvt, Wot);

  const float qscale = 0.125f * 1.44269504088896340736f;  // (1/sqrt(64)) * log2(e)
  gemm_qkv<<<768, 256, 0, stream>>>(Xq, Xk, Xv, Wqt, Wkt, Wvt, bq, bk, bv,
                                    Qb, Kb, Vtb, qscale);

  attn<<<512, 256, 0, stream>>>(Qb, Kb, Vtb, AO);

  gemm_out<<<512, 256, 0, stream>>>(AO, Wot, bo, out);
}

// Round 17
// 124.163 us; speedup vs baseline: 1.0669x; 1.0669x over previous
//
#include <hip/hip_runtime.h>
#include <hip/hip_bf16.h>

// Problem: B=2, S=2048, E=1024, H=16, D=64. All inputs fp32, output fp32.
// Pipeline: prep (cvt X->bf16 + wtrans W->bf16 [N][K], one launch)
//           | fused QKV GEMM (grid.z folded into 1D XCD-chunked id, BN=128,
//           2-phase prefetch) -> Q(scaled log2e/8),K [BH][S][D],
//           V^T [BH][D][S_perm] | flash attention (r12-verified) | GEMM BN=64
//           (XCD-chunked) -> fp32 + bo.
// LDS tiles: T2 XOR swizzle byte ^= ((row&7)<<4) within 128B rows; staged via
// global_load_lds with inverse-swizzled global source (linear LDS dest).
// History: r3 dbuf+counted-vmcnt raced -> full-drain barriers only.
//          r7 zero-staging attn latency-bound -> LDS staging mandatory.
//          r8 AF32 cvt-fusion regressed -> separate cvt pass.
//          r11 permlane32_swap self-swap reduce FAILED -> shfl_xor merges.
//          r13 split-K=2 REGRESSED (LDS-capped occupancy) -> reverted.
//          r14 GEMM 2-phase prefetch: 138.8->133.5. r15 prep-merge + T1
//          XCD-chunk: 133.5->124.1.
//          r16 KVBLK=128/4-wave REGRESSED (65->73us: fewer blocks/CU ->
//          lost block-level TLP; 4-wave barrier lockstep) -> reverted to
//          r15 session-best configuration.

#define EMBED 1024
#define NHEAD 16
#define HDIM 64
#define SEQ 2048
#define MROWS 4096  // B*S

typedef __attribute__((ext_vector_type(8))) __bf16 bf16x8;
typedef __attribute__((ext_vector_type(4))) float f32x4;
typedef __attribute__((ext_vector_type(16))) float f32x16;

__device__ __forceinline__ unsigned short f2bf(float f) {
  unsigned int u = __builtin_bit_cast(unsigned int, f);
  u += 0x7fffu + ((u >> 16) & 1u);  // round-to-nearest-even
  return (unsigned short)(u >> 16);
}

// packed f32x2 -> bf16x2 (T12 recipe; no builtin on gfx950)
__device__ __forceinline__ int cvtpk_bf16(float lo, float hi) {
  int r;
  asm("v_cvt_pk_bf16_f32 %0, %1, %2" : "=v"(r) : "v"(lo), "v"(hi));
  return r;
}

__device__ __forceinline__ float max3f(float a, float b, float c) {
  return fmaxf(fmaxf(a, b), c);  // clang fuses to v_max3_f32
}

// swizzled byte offset within a [rows][128B] LDS tile
__device__ __forceinline__ int swz(int row, int bcol) {
  return row * 128 + (bcol ^ ((row & 7) << 4));
}

// async global->LDS, 16B per lane. LDS dest = base + lane*16 (linear).
__device__ __forceinline__ void gload16(const void* g, void* l) {
  __builtin_amdgcn_global_load_lds((const __attribute__((address_space(1))) void*)g,
                                   (__attribute__((address_space(3))) void*)l, 16, 0, 0);
}

// ---- prep: blocks 0..6143 = fp32->bf16 cvt of q/k/v (8 elts/thread);
//            blocks 6144..7167 = W [K][N] fp32 -> Wt [N][K] bf16 transpose.
__global__ __launch_bounds__(256) void prep(const float* __restrict__ q32, const float* __restrict__ k32,
                                            const float* __restrict__ v32,
                                            unsigned short* __restrict__ Xq, unsigned short* __restrict__ Xk,
                                            unsigned short* __restrict__ Xv,
                                            const float* __restrict__ w0, const float* __restrict__ w1,
                                            const float* __restrict__ w2, const float* __restrict__ w3,
                                            unsigned short* __restrict__ o0, unsigned short* __restrict__ o1,
                                            unsigned short* __restrict__ o2, unsigned short* __restrict__ o3) {
  __shared__ float tile[64][65];  // used by wtrans branch only
  const int id = blockIdx.x;
  if (id < 6144) {
    const float* in; unsigned short* out;
    switch (id >> 11) {
      case 0: in = q32; out = Xq; break;
      case 1: in = k32; out = Xk; break;
      default: in = v32; out = Xv; break;
    }
    int i = (id & 2047) * 256 + threadIdx.x;
    const float4* p = reinterpret_cast<const float4*>(in) + (size_t)i * 2;
    float4 a = p[0], b = p[1];
    int4 r;
    r.x = cvtpk_bf16(a.x, a.y);
    r.y = cvtpk_bf16(a.z, a.w);
    r.z = cvtpk_bf16(b.x, b.y);
    r.w = cvtpk_bf16(b.z, b.w);
    reinterpret_cast<int4*>(out)[i] = r;
  } else {
    const int wid = id - 6144;
    const float* src; unsigned short* dst;
    switch (wid >> 8) {
      case 0: src = w0; dst = o0; break;
      case 1: src = w1; dst = o1; break;
      case 2: src = w2; dst = o2; break;
      default: src = w3; dst = o3; break;
    }
    const int k0 = ((wid >> 4) & 15) * 64, n0 = (wid & 15) * 64;
    const int c = threadIdx.x & 63, r0 = threadIdx.x >> 6;
#pragma unroll
    for (int i = 0; i < 16; ++i) {
      int r = r0 + i * 4;
      tile[r][c] = src[(size_t)(k0 + r) * EMBED + n0 + c];
    }
    __syncthreads();
#pragma unroll
    for (int i = 0; i < 16; ++i) {
      int nr = r0 + i * 4;
      dst[(size_t)(n0 + nr) * EMBED + k0 + c] = f2bf(tile[c][nr]);
    }
  }
}

// ---- shared GEMM core: C[128 x BN tile at (m0,n0)] = A @ Bt^T + bias ----
// A bf16 [M][K]; Bt bf16 [N][K]. Staging via global_load_lds (m97 pattern),
// 2-phase prefetch (r14-verified): {drain-barrier; ds_read ALL frags -> regs;
// read-barrier; gload(next) into same buffer; MFMA}.
// BN=128: waves 2x2, acc[4][4].  BN=64: waves 4x1, acc[2][4].
// mode 0: bf16 scatter to [B*H][S][D]; mode 1: fp32 row-major;
// mode 2: bf16 V^T scatter to [B*H][D][S] with seq-quartet bit-swap
//         (s-quartet q -> position-quartet ((q&1)<<1)|(q>>1)) so attn's PV
//         in-lane A-fragment permutation is compensated in V's layout.
template <int BN>
__device__ __forceinline__ void gemm_core(const unsigned short* __restrict__ A,
                                          const unsigned short* __restrict__ Bt,
                                          const float* __restrict__ bias,
                                          void* __restrict__ C, float oscale, int mode,
                                          int m0, int n0) {
  constexpr int K = EMBED;
  constexpr int MF = (BN == 128) ? 4 : 2;     // 16-row fragments per wave (M)
  constexpr int BRW = BN / 4;                 // B rows staged per wave
  __shared__ __align__(16) unsigned short Alds[128 * 64];
  __shared__ __align__(16) unsigned short Blds[BN * 64];
  char* Ab8 = (char*)Alds; char* Bb8 = (char*)Blds;
  const char* AB = (const char*)A;
  const char* BB = (const char*)Bt;
  const int tid = threadIdx.x;
  const int lane = tid & 63, w = tid >> 6;
  const int wr = (BN == 128) ? (w >> 1) : w;
  const int wc = (BN == 128) ? (w & 1) : 0;
  const int fr = lane & 15, fq = lane >> 4;
  const int bcol = (lane & 7) * 16;
  const int gsc = bcol ^ ((lane >> 3) << 4);  // row&7 == lane>>3 for all staged rows

  f32x4 acc[MF][4];
#pragma unroll
  for (int m = 0; m < MF; ++m)
#pragma unroll
    for (int n = 0; n < 4; ++n) acc[m][n] = f32x4{0.f, 0.f, 0.f, 0.f};

#define GSTAGE(k0_)                                                                          \
  {                                                                                          \
    _Pragma("unroll") for (int i_ = 0; i_ < 4; ++i_) {                                       \
      int row_ = w * 32 + i_ * 8 + (lane >> 3);                                              \
      gload16(AB + (size_t)(m0 + row_) * (K * 2) + (k0_)*2 + gsc, Ab8 + w * 4096 + i_ * 1024); \
    }                                                                                        \
    _Pragma("unroll") for (int i_ = 0; i_ < BRW / 8; ++i_) {                                 \
      int row_ = w * BRW + i_ * 8 + (lane >> 3);                                             \
      gload16(BB + (size_t)(n0 + row_) * (K * 2) + (k0_)*2 + gsc,                            \
              Bb8 + w * (BRW * 128) + i_ * 1024);                                            \
    }                                                                                        \
  }

  GSTAGE(0);  // prologue

  for (int k0 = 0; k0 < K; k0 += 64) {
    __syncthreads();  // drains vmcnt(0): tile k0 fully staged
    // ds_read ALL fragments of tile k0 into registers
    bf16x8 af2[2][MF], bf2[2][4];
#pragma unroll
    for (int ks = 0; ks < 2; ++ks) {
#pragma unroll
      for (int m = 0; m < MF; ++m) {
        int ar = wr * (MF * 16) + m * 16 + fr;
        af2[ks][m] = *reinterpret_cast<const bf16x8*>(Ab8 + swz(ar, ks * 64 + fq * 16));
      }
#pragma unroll
      for (int n = 0; n < 4; ++n) {
        int br = wc * 64 + n * 16 + fr;
        bf2[ks][n] = *reinterpret_cast<const bf16x8*>(Bb8 + swz(br, ks * 64 + fq * 16));
      }
    }
    __syncthreads();  // all waves done reading -> buffer free for prefetch
    if (k0 + 64 < K) GSTAGE(k0 + 64);  // async prefetch; hides under MFMA
#pragma unroll
    for (int ks = 0; ks < 2; ++ks)
#pragma unroll
      for (int m = 0; m < MF; ++m)
#pragma unroll
        for (int n = 0; n < 4; ++n)
          acc[m][n] = __builtin_amdgcn_mfma_f32_16x16x32_bf16(af2[ks][m], bf2[ks][n], acc[m][n], 0, 0, 0);
  }
#undef GSTAGE

#pragma unroll
  for (int n = 0; n < 4; ++n) {
    int col = n0 + wc * 64 + n * 16 + fr;
    float bv = bias[col];
#pragma unroll
    for (int m = 0; m < MF; ++m) {
      int rowb = m0 + wr * (MF * 16) + m * 16 + fq * 4;
      if (mode == 2) {
        int b = rowb >> 11, s0 = rowb & (SEQ - 1);
        // seq-quartet bit-swap: quartet q -> ((q&1)<<1)|(q>>1) within each 16
        int s0p = (s0 & ~12) | ((s0 & 4) << 1) | ((s0 & 8) >> 1);
        int h = col >> 6, d = col & 63;
        int2 pk;
        pk.x = cvtpk_bf16((acc[m][n][0] + bv) * oscale, (acc[m][n][1] + bv) * oscale);
        pk.y = cvtpk_bf16((acc[m][n][2] + bv) * oscale, (acc[m][n][3] + bv) * oscale);
        *reinterpret_cast<int2*>(
            &reinterpret_cast<unsigned short*>(C)[((size_t)((b * NHEAD + h) * HDIM + d)) * SEQ + s0p]) = pk;
      } else if (mode == 0) {
#pragma unroll
        for (int r = 0; r < 4; ++r) {
          int row = rowb + r;
          float v = (acc[m][n][r] + bv) * oscale;
          int b = row >> 11, s = row & (SEQ - 1), h = col >> 6, d = col & 63;
          reinterpret_cast<unsigned short*>(C)[((size_t)((b * NHEAD + h) * SEQ + s) << 6) + d] = f2bf(v);
        }
      } else {
#pragma unroll
        for (int r = 0; r < 4; ++r)
          reinterpret_cast<float*>(C)[(size_t)(rowb + r) * EMBED + col] = acc[m][n][r] + bv;
      }
    }
  }
}

// fused QKV projection, 1D grid of 768 with XCD-chunked swizzle:
// logical lg = (id%8)*96 + id/8 so lg-consecutive blocks (sharing an A
// row-panel) land on one XCD's L2. lg order: (z, by, bx) with 8 bx.
__global__ __launch_bounds__(256) void gemm_qkv(
    const unsigned short* __restrict__ Xq, const unsigned short* __restrict__ Xk,
    const unsigned short* __restrict__ Xv,
    const unsigned short* __restrict__ Wqt, const unsigned short* __restrict__ Wkt,
    const unsigned short* __restrict__ Wvt,
    const float* __restrict__ bq, const float* __restrict__ bk, const float* __restrict__ bv,
    unsigned short* __restrict__ Qb, unsigned short* __restrict__ Kb,
    unsigned short* __restrict__ Vtb, float qscale) {
  const int id = blockIdx.x;
  const int lg = (id & 7) * 96 + (id >> 3);  // bijective: 768 = 8*96
  const int z = lg >> 8, rem = lg & 255;
  const int m0 = (rem >> 3) * 128, n0 = (rem & 7) * 128;
  switch (z) {
    case 0: gemm_core<128>(Xq, Wqt, bq, Qb, qscale, 0, m0, n0); break;
    case 1: gemm_core<128>(Xk, Wkt, bk, Kb, 1.0f, 0, m0, n0); break;
    default: gemm_core<128>(Xv, Wvt, bv, Vtb, 1.0f, 2, m0, n0); break;
  }
}

// output GEMM: 128x64 tiles, 1D grid of 512, XCD-chunked (lg=(id%8)*64+id/8;
// lg order (by, bx) with 16 bx -> same-panel blocks on one XCD).
__global__ __launch_bounds__(256) void gemm_out(const unsigned short* __restrict__ A,
                                                const unsigned short* __restrict__ Bt,
                                                const float* __restrict__ bias,
                                                float* __restrict__ C) {
  const int id = blockIdx.x;
  const int lg = (id & 7) * 64 + (id >> 3);  // bijective: 512 = 8*64
  const int m0 = (lg >> 4) * 128, n0 = (lg & 15) * 64;
  gemm_core<64>(A, Bt, bias, C, 1.0f, 1, m0, n0);
}

// ---- flash attention, 32x32x16 MFMA (r12-verified, unchanged) ----
// Q,K bf16 [B*H][S][D] (Q pre-scaled by log2e/8); Vt bf16 [B*H][D][S_perm].
// 2 waves x 32 q-rows per block. Lane: ql=lane&31 (q), t=lane>>5.
// QK: sc[kb] = mfma_32x32x16(Kfrag, Qfrag) -> C[k][q]: col q=ql, row
//   k=(reg&3)+8*(reg>>2)+4t within kb*32. [guide-verified C/D layout]
// Softmax in-lane (max3 tree); ONE __shfl_xor(32) per tile (max merge).
// lrow LANE-LOCAL per tile; single cross-half shfl merge in the epilogue.
// PV: A=P from own regs (V^T's bit-swapped seq layout compensates).
// Staging: r9-verified gload_lds prefetch dbuf + 1 full-drain barrier/tile.
__global__ __launch_bounds__(128) void attn(const unsigned short* __restrict__ Q,
                                            const unsigned short* __restrict__ Kk,
                                            const unsigned short* __restrict__ Vt,
                                            unsigned short* __restrict__ AO) {
  __shared__ __align__(16) unsigned short Klds[2][64 * 64];
  __shared__ __align__(16) unsigned short Vlds[2][64 * 64];  // [d][k_perm]
  const int tid = threadIdx.x, lane = tid & 63, w = tid >> 6;  // w in {0,1}
  const int ql = lane & 31, t = lane >> 5;

  // XCD swizzle: all 32 q-blocks of a head on one XCD (round-robin lin%8).
  const int lin = blockIdx.x;
  const int head = (lin & 7) * 4 + ((lin >> 3) & 3);
  const int q0 = (lin >> 5) * 64;
  const size_t hb = (size_t)head * SEQ * HDIM;
  const unsigned short* Qh = Q + hb;
  const char* KhB = (const char*)(Kk + hb);
  const char* VhB = (const char*)(Vt + hb);  // rows d, 4096B each

  // staging addressing (both-sides swizzle, rule #21)
  const int gsc = ((lane & 7) * 16) ^ ((lane >> 3) << 4);
  const int row0 = w * 32 + (lane >> 3);  // +i*8, i=0..3 -> 32 rows/wave

#define STAGE(kt_, b_)                                                                     \
  {                                                                                        \
    char* kb_ = (char*)Klds[b_];                                                           \
    char* vb_ = (char*)Vlds[b_];                                                           \
    _Pragma("unroll") for (int i_ = 0; i_ < 4; ++i_) {                                     \
      gload16(KhB + (size_t)((kt_)*64 + row0 + i_ * 8) * 128 + gsc,                        \
              kb_ + w * 4096 + i_ * 1024);                                                 \
      gload16(VhB + (size_t)(row0 + i_ * 8) * (SEQ * 2) + (kt_)*128 + gsc,                 \
              vb_ + w * 4096 + i_ * 1024);                                                 \
    }                                                                                      \
  }

  // Q fragments (B-operand): lane supplies Q[ql][d = s*16 + t*8 + e]
  bf16x8 qf[4];
  {
    const unsigned short* qp = Qh + (size_t)(q0 + w * 32 + ql) * HDIM + t * 8;
    qf[0] = *reinterpret_cast<const bf16x8*>(qp);
    qf[1] = *reinterpret_cast<const bf16x8*>(qp + 16);
    qf[2] = *reinterpret_cast<const bf16x8*>(qp + 32);
    qf[3] = *reinterpret_cast<const bf16x8*>(qp + 48);
  }
  f32x16 oacc0 = {}, oacc1 = {};  // d-blocks 0..31, 32..63
  float mrow = -1e30f, lrow = 0.f;  // lrow LANE-LOCAL (half-sum); merged at end

  STAGE(0, 0);
  __syncthreads();  // drains vmcnt(0) -> tile 0 staged

  for (int kt = 0; kt < SEQ / 64; ++kt) {
    const int cur = kt & 1;
    const bool more = (kt + 1 < SEQ / 64);
    if (more) STAGE(kt + 1, cur ^ 1);  // async prefetch; drained by tile-end barrier
    char* Kb8 = (char*)Klds[cur];
    char* Vb8 = (char*)Vlds[cur];

    // S^T = K.Q^T (log2 domain): sc0 = keys kb=0 (k 0..31), sc1 = kb=1
    f32x16 sc0 = {}, sc1 = {};
    __builtin_amdgcn_s_setprio(1);
#pragma unroll
    for (int s = 0; s < 4; ++s) {
      bf16x8 kf0 = *reinterpret_cast<const bf16x8*>(Kb8 + swz(ql, s * 32 + t * 16));
      bf16x8 kf1 = *reinterpret_cast<const bf16x8*>(Kb8 + swz(32 + ql, s * 32 + t * 16));
      sc0 = __builtin_amdgcn_mfma_f32_32x32x16_bf16(kf0, qf[s], sc0, 0, 0, 0);
      sc1 = __builtin_amdgcn_mfma_f32_32x32x16_bf16(kf1, qf[s], sc1, 0, 0, 0);
    }
    __builtin_amdgcn_s_setprio(0);

    // in-lane max over 32 scores (max3 tree), cross-half via verified shfl_xor
    float l1[12];
#pragma unroll
    for (int i = 0; i < 5; ++i) l1[i] = max3f(sc0[3 * i], sc0[3 * i + 1], sc0[3 * i + 2]);
#pragma unroll
    for (int i = 0; i < 5; ++i) l1[5 + i] = max3f(sc1[3 * i], sc1[3 * i + 1], sc1[3 * i + 2]);
    l1[10] = sc0[15];
    l1[11] = sc1[15];
    float l2a = max3f(l1[0], l1[1], l1[2]);
    float l2b = max3f(l1[3], l1[4], l1[5]);
    float l2c = max3f(l1[6], l1[7], l1[8]);
    float l2d = max3f(l1[9], l1[10], l1[11]);
    float mt = fmaxf(max3f(l2a, l2b, l2c), l2d);
    mt = fmaxf(mt, __shfl_xor(mt, 32));

    // T13 defer-max: only rescale when some row's max grew past 2^8 headroom
    if (!__all(mt <= mrow + 8.0f)) {
      float mn = fmaxf(mrow, mt);
      float resc = __builtin_amdgcn_exp2f(mrow - mn);
      lrow *= resc;
#pragma unroll
      for (int r = 0; r < 16; ++r) {
        float rq = __shfl(resc, (r & 3) + 8 * (r >> 2) + 4 * t, 64);
        oacc0[r] *= rq;
        oacc1[r] *= rq;
      }
      mrow = mn;
    }

    // P = exp2(S - mrow) in place; lane-local partial sums (no per-tile merge)
    float ps0 = 0.f, ps1 = 0.f, ps2 = 0.f, ps3 = 0.f;
#pragma unroll
    for (int i = 0; i < 4; ++i) {
      sc0[4 * i + 0] = __builtin_amdgcn_exp2f(sc0[4 * i + 0] - mrow);
      sc0[4 * i + 1] = __builtin_amdgcn_exp2f(sc0[4 * i + 1] - mrow);
      sc0[4 * i + 2] = __builtin_amdgcn_exp2f(sc0[4 * i + 2] - mrow);
      sc0[4 * i + 3] = __builtin_amdgcn_exp2f(sc0[4 * i + 3] - mrow);
      sc1[4 * i + 0] = __builtin_amdgcn_exp2f(sc1[4 * i + 0] - mrow);
      sc1[4 * i + 1] = __builtin_amdgcn_exp2f(sc1[4 * i + 1] - mrow);
      sc1[4 * i + 2] = __builtin_amdgcn_exp2f(sc1[4 * i + 2] - mrow);
      sc1[4 * i + 3] = __builtin_amdgcn_exp2f(sc1[4 * i + 3] - mrow);
      ps0 += sc0[4 * i + 0] + sc0[4 * i + 1];
      ps1 += sc0[4 * i + 2] + sc0[4 * i + 3];
      ps2 += sc1[4 * i + 0] + sc1[4 * i + 1];
      ps3 += sc1[4 * i + 2] + sc1[4 * i + 3];
    }
    lrow += (ps0 + ps1) + (ps2 + ps3);

    // PA fragments: pa[s] = own regs 8*(s&1)..+7 of sc[s>>1] (no cross-lane;
    // slot->k quartet permutation is baked into V^T's global layout)
    int4 paw[4];
#pragma unroll
    for (int s2 = 0; s2 < 2; ++s2) {
      paw[s2].x     = cvtpk_bf16(sc0[8 * s2 + 0], sc0[8 * s2 + 1]);
      paw[s2].y     = cvtpk_bf16(sc0[8 * s2 + 2], sc0[8 * s2 + 3]);
      paw[s2].z     = cvtpk_bf16(sc0[8 * s2 + 4], sc0[8 * s2 + 5]);
      paw[s2].w     = cvtpk_bf16(sc0[8 * s2 + 6], sc0[8 * s2 + 7]);
      paw[2 + s2].x = cvtpk_bf16(sc1[8 * s2 + 0], sc1[8 * s2 + 1]);
      paw[2 + s2].y = cvtpk_bf16(sc1[8 * s2 + 2], sc1[8 * s2 + 3]);
      paw[2 + s2].z = cvtpk_bf16(sc1[8 * s2 + 4], sc1[8 * s2 + 5]);
      paw[2 + s2].w = cvtpk_bf16(sc1[8 * s2 + 6], sc1[8 * s2 + 7]);
    }

    // PV: O[q][d] += P.V; V-fragment (B-operand) rows d, positions s*16+slot
    __builtin_amdgcn_s_setprio(1);
#pragma unroll
    for (int s = 0; s < 4; ++s) {
      bf16x8 pa = __builtin_bit_cast(bf16x8, paw[s]);
      bf16x8 v0 = *reinterpret_cast<const bf16x8*>(Vb8 + swz(ql, s * 32 + t * 16));
      bf16x8 v1 = *reinterpret_cast<const bf16x8*>(Vb8 + swz(32 + ql, s * 32 + t * 16));
      oacc0 = __builtin_amdgcn_mfma_f32_32x32x16_bf16(pa, v0, oacc0, 0, 0, 0);
      oacc1 = __builtin_amdgcn_mfma_f32_32x32x16_bf16(pa, v1, oacc1, 0, 0, 0);
    }
    __builtin_amdgcn_s_setprio(0);

    __syncthreads();  // all waves done reading cur + prefetch drained (vmcnt 0)
  }
#undef STAGE

  // merge the two half-sums of lrow once (was 32 per-tile shuffles)
  lrow += __shfl_xor(lrow, 32);

  const int b = head >> 4, hh = head & 15;
#pragma unroll
  for (int r = 0; r < 16; ++r) {
    int qr = (r & 3) + 8 * (r >> 2) + 4 * t;
    float inv = 1.0f / __shfl(lrow, qr, 64);
    int srow = q0 + w * 32 + qr;
    size_t ob = (size_t)(b * SEQ + srow) * EMBED + hh * 64 + ql;
    AO[ob] = f2bf(oacc0[r] * inv);
    AO[ob + 32] = f2bf(oacc1[r] * inv);
  }
}

extern "C" void kernel_launch(void* const* d_in, const int* in_sizes, int n_in,
                              void* d_out, int out_size, void* d_ws, size_t ws_size,
                              hipStream_t stream) {
  const float* q32 = (const float*)d_in[0];
  const float* k32 = (const float*)d_in[1];
  const float* v32 = (const float*)d_in[2];
  const float* Wq = (const float*)d_in[3]; const float* bq = (const float*)d_in[4];
  const float* Wk = (const float*)d_in[5]; const float* bk = (const float*)d_in[6];
  const float* Wv = (const float*)d_in[7]; const float* bv = (const float*)d_in[8];
  const float* Wo = (const float*)d_in[9]; const float* bo = (const float*)d_in[10];
  float* out = (float*)d_out;

  char* ws = (char*)d_ws;
  const size_t MB = 1u << 20;
  unsigned short* Xq  = (unsigned short*)(ws + 0 * MB);
  unsigned short* Xk  = (unsigned short*)(ws + 8 * MB);
  unsigned short* Xv  = (unsigned short*)(ws + 16 * MB);
  unsigned short* Wqt = (unsigned short*)(ws + 24 * MB);
  unsigned short* Wkt = (unsigned short*)(ws + 26 * MB);
  unsigned short* Wvt = (unsigned short*)(ws + 28 * MB);
  unsigned short* Wot = (unsigned short*)(ws + 30 * MB);
  unsigned short* Qb  = (unsigned short*)(ws + 32 * MB);
  unsigned short* Kb  = (unsigned short*)(ws + 40 * MB);
  unsigned short* Vtb = (unsigned short*)(ws + 48 * MB);
  unsigned short* AO  = Xq;  // safe: GEMM-Q (sole Xq reader) completes before attn writes

  prep<<<7168, 256, 0, stream>>>(q32, k32, v32, Xq, Xk, Xv,
                                 Wq, Wk, Wv, Wo, Wqt, Wkt, Wvt, Wot);

  const float qscale = 0.125f * 1.44269504088896340736f;  // (1/sqrt(64)) * log2(e)
  gemm_qkv<<<768, 256, 0, stream>>>(Xq, Xk, Xv, Wqt, Wkt, Wvt, bq, bk, bv,
                                    Qb, Kb, Vtb, qscale);

  attn<<<dim3(SEQ / 64 * 32), 128, 0, stream>>>(Qb, Kb, Vtb, AO);

  gemm_out<<<512, 256, 0, stream>>>(AO, Wot, bo, out);
}

// Round 18
// 123.957 us; speedup vs baseline: 1.0687x; 1.0017x over previous
//
#include <hip/hip_runtime.h>
#include <hip/hip_bf16.h>

// Problem: B=2, S=2048, E=1024, H=16, D=64. All inputs fp32, output fp32.
// Pipeline: prep (cvt X->bf16 + wtrans W->bf16 [N][K], one launch)
//           | fused QKV GEMM (1D XCD-chunked, BN=128, 2-phase prefetch)
//           -> Q(scaled log2e/8),K [BH][S][D], V^T [BH][D][S_perm]
//           | flash attention (r12-verified structure; r18: softmax/PV
//           half-tile interleave so PV MFMAs of half 0 issue before exp2 of
//           half 1 -- MFMA pipe overlaps VALU within the wave)
//           | GEMM BN=64 (XCD-chunked) -> fp32 + bo.
// LDS tiles: T2 XOR swizzle byte ^= ((row&7)<<4) within 128B rows; staged via
// global_load_lds with inverse-swizzled global source (linear LDS dest).
// History: r3 dbuf+counted-vmcnt raced -> full-drain barriers only.
//          r7 zero-staging attn latency-bound -> LDS staging mandatory.
//          r8 AF32 cvt-fusion regressed -> separate cvt pass.
//          r11 permlane32_swap self-swap reduce FAILED -> shfl_xor merges.
//          r13 split-K=2 REGRESSED (LDS-capped occupancy) -> reverted.
//          r14 GEMM 2-phase prefetch: 138.8->133.5. r15 prep-merge + T1
//          XCD-chunk: 133.5->124.1.
//          r16 KVBLK=128/4-wave REGRESSED (fewer blocks/CU) -> reverted.
//          r18: attn softmax/PV interleave (pure reorder, no sync change).

#define EMBED 1024
#define NHEAD 16
#define HDIM 64
#define SEQ 2048
#define MROWS 4096  // B*S

typedef __attribute__((ext_vector_type(8))) __bf16 bf16x8;
typedef __attribute__((ext_vector_type(4))) float f32x4;
typedef __attribute__((ext_vector_type(16))) float f32x16;

__device__ __forceinline__ unsigned short f2bf(float f) {
  unsigned int u = __builtin_bit_cast(unsigned int, f);
  u += 0x7fffu + ((u >> 16) & 1u);  // round-to-nearest-even
  return (unsigned short)(u >> 16);
}

// packed f32x2 -> bf16x2 (T12 recipe; no builtin on gfx950)
__device__ __forceinline__ int cvtpk_bf16(float lo, float hi) {
  int r;
  asm("v_cvt_pk_bf16_f32 %0, %1, %2" : "=v"(r) : "v"(lo), "v"(hi));
  return r;
}

__device__ __forceinline__ float max3f(float a, float b, float c) {
  return fmaxf(fmaxf(a, b), c);  // clang fuses to v_max3_f32
}

// swizzled byte offset within a [rows][128B] LDS tile
__device__ __forceinline__ int swz(int row, int bcol) {
  return row * 128 + (bcol ^ ((row & 7) << 4));
}

// async global->LDS, 16B per lane. LDS dest = base + lane*16 (linear).
__device__ __forceinline__ void gload16(const void* g, void* l) {
  __builtin_amdgcn_global_load_lds((const __attribute__((address_space(1))) void*)g,
                                   (__attribute__((address_space(3))) void*)l, 16, 0, 0);
}

// ---- prep: blocks 0..6143 = fp32->bf16 cvt of q/k/v (8 elts/thread);
//            blocks 6144..7167 = W [K][N] fp32 -> Wt [N][K] bf16 transpose.
__global__ __launch_bounds__(256) void prep(const float* __restrict__ q32, const float* __restrict__ k32,
                                            const float* __restrict__ v32,
                                            unsigned short* __restrict__ Xq, unsigned short* __restrict__ Xk,
                                            unsigned short* __restrict__ Xv,
                                            const float* __restrict__ w0, const float* __restrict__ w1,
                                            const float* __restrict__ w2, const float* __restrict__ w3,
                                            unsigned short* __restrict__ o0, unsigned short* __restrict__ o1,
                                            unsigned short* __restrict__ o2, unsigned short* __restrict__ o3) {
  __shared__ float tile[64][65];  // used by wtrans branch only
  const int id = blockIdx.x;
  if (id < 6144) {
    const float* in; unsigned short* out;
    switch (id >> 11) {
      case 0: in = q32; out = Xq; break;
      case 1: in = k32; out = Xk; break;
      default: in = v32; out = Xv; break;
    }
    int i = (id & 2047) * 256 + threadIdx.x;
    const float4* p = reinterpret_cast<const float4*>(in) + (size_t)i * 2;
    float4 a = p[0], b = p[1];
    int4 r;
    r.x = cvtpk_bf16(a.x, a.y);
    r.y = cvtpk_bf16(a.z, a.w);
    r.z = cvtpk_bf16(b.x, b.y);
    r.w = cvtpk_bf16(b.z, b.w);
    reinterpret_cast<int4*>(out)[i] = r;
  } else {
    const int wid = id - 6144;
    const float* src; unsigned short* dst;
    switch (wid >> 8) {
      case 0: src = w0; dst = o0; break;
      case 1: src = w1; dst = o1; break;
      case 2: src = w2; dst = o2; break;
      default: src = w3; dst = o3; break;
    }
    const int k0 = ((wid >> 4) & 15) * 64, n0 = (wid & 15) * 64;
    const int c = threadIdx.x & 63, r0 = threadIdx.x >> 6;
#pragma unroll
    for (int i = 0; i < 16; ++i) {
      int r = r0 + i * 4;
      tile[r][c] = src[(size_t)(k0 + r) * EMBED + n0 + c];
    }
    __syncthreads();
#pragma unroll
    for (int i = 0; i < 16; ++i) {
      int nr = r0 + i * 4;
      dst[(size_t)(n0 + nr) * EMBED + k0 + c] = f2bf(tile[c][nr]);
    }
  }
}

// ---- shared GEMM core: C[128 x BN tile at (m0,n0)] = A @ Bt^T + bias ----
// A bf16 [M][K]; Bt bf16 [N][K]. Staging via global_load_lds (m97 pattern),
// 2-phase prefetch (r14-verified): {drain-barrier; ds_read ALL frags -> regs;
// read-barrier; gload(next) into same buffer; MFMA}.
// BN=128: waves 2x2, acc[4][4].  BN=64: waves 4x1, acc[2][4].
// mode 0: bf16 scatter to [B*H][S][D]; mode 1: fp32 row-major;
// mode 2: bf16 V^T scatter to [B*H][D][S] with seq-quartet bit-swap
//         (s-quartet q -> position-quartet ((q&1)<<1)|(q>>1)) so attn's PV
//         in-lane A-fragment permutation is compensated in V's layout.
template <int BN>
__device__ __forceinline__ void gemm_core(const unsigned short* __restrict__ A,
                                          const unsigned short* __restrict__ Bt,
                                          const float* __restrict__ bias,
                                          void* __restrict__ C, float oscale, int mode,
                                          int m0, int n0) {
  constexpr int K = EMBED;
  constexpr int MF = (BN == 128) ? 4 : 2;     // 16-row fragments per wave (M)
  constexpr int BRW = BN / 4;                 // B rows staged per wave
  __shared__ __align__(16) unsigned short Alds[128 * 64];
  __shared__ __align__(16) unsigned short Blds[BN * 64];
  char* Ab8 = (char*)Alds; char* Bb8 = (char*)Blds;
  const char* AB = (const char*)A;
  const char* BB = (const char*)Bt;
  const int tid = threadIdx.x;
  const int lane = tid & 63, w = tid >> 6;
  const int wr = (BN == 128) ? (w >> 1) : w;
  const int wc = (BN == 128) ? (w & 1) : 0;
  const int fr = lane & 15, fq = lane >> 4;
  const int bcol = (lane & 7) * 16;
  const int gsc = bcol ^ ((lane >> 3) << 4);  // row&7 == lane>>3 for all staged rows

  f32x4 acc[MF][4];
#pragma unroll
  for (int m = 0; m < MF; ++m)
#pragma unroll
    for (int n = 0; n < 4; ++n) acc[m][n] = f32x4{0.f, 0.f, 0.f, 0.f};

#define GSTAGE(k0_)                                                                          \
  {                                                                                          \
    _Pragma("unroll") for (int i_ = 0; i_ < 4; ++i_) {                                       \
      int row_ = w * 32 + i_ * 8 + (lane >> 3);                                              \
      gload16(AB + (size_t)(m0 + row_) * (K * 2) + (k0_)*2 + gsc, Ab8 + w * 4096 + i_ * 1024); \
    }                                                                                        \
    _Pragma("unroll") for (int i_ = 0; i_ < BRW / 8; ++i_) {                                 \
      int row_ = w * BRW + i_ * 8 + (lane >> 3);                                             \
      gload16(BB + (size_t)(n0 + row_) * (K * 2) + (k0_)*2 + gsc,                            \
              Bb8 + w * (BRW * 128) + i_ * 1024);                                            \
    }                                                                                        \
  }

  GSTAGE(0);  // prologue

  for (int k0 = 0; k0 < K; k0 += 64) {
    __syncthreads();  // drains vmcnt(0): tile k0 fully staged
    // ds_read ALL fragments of tile k0 into registers
    bf16x8 af2[2][MF], bf2[2][4];
#pragma unroll
    for (int ks = 0; ks < 2; ++ks) {
#pragma unroll
      for (int m = 0; m < MF; ++m) {
        int ar = wr * (MF * 16) + m * 16 + fr;
        af2[ks][m] = *reinterpret_cast<const bf16x8*>(Ab8 + swz(ar, ks * 64 + fq * 16));
      }
#pragma unroll
      for (int n = 0; n < 4; ++n) {
        int br = wc * 64 + n * 16 + fr;
        bf2[ks][n] = *reinterpret_cast<const bf16x8*>(Bb8 + swz(br, ks * 64 + fq * 16));
      }
    }
    __syncthreads();  // all waves done reading -> buffer free for prefetch
    if (k0 + 64 < K) GSTAGE(k0 + 64);  // async prefetch; hides under MFMA
#pragma unroll
    for (int ks = 0; ks < 2; ++ks)
#pragma unroll
      for (int m = 0; m < MF; ++m)
#pragma unroll
        for (int n = 0; n < 4; ++n)
          acc[m][n] = __builtin_amdgcn_mfma_f32_16x16x32_bf16(af2[ks][m], bf2[ks][n], acc[m][n], 0, 0, 0);
  }
#undef GSTAGE

#pragma unroll
  for (int n = 0; n < 4; ++n) {
    int col = n0 + wc * 64 + n * 16 + fr;
    float bv = bias[col];
#pragma unroll
    for (int m = 0; m < MF; ++m) {
      int rowb = m0 + wr * (MF * 16) + m * 16 + fq * 4;
      if (mode == 2) {
        int b = rowb >> 11, s0 = rowb & (SEQ - 1);
        // seq-quartet bit-swap: quartet q -> ((q&1)<<1)|(q>>1) within each 16
        int s0p = (s0 & ~12) | ((s0 & 4) << 1) | ((s0 & 8) >> 1);
        int h = col >> 6, d = col & 63;
        int2 pk;
        pk.x = cvtpk_bf16((acc[m][n][0] + bv) * oscale, (acc[m][n][1] + bv) * oscale);
        pk.y = cvtpk_bf16((acc[m][n][2] + bv) * oscale, (acc[m][n][3] + bv) * oscale);
        *reinterpret_cast<int2*>(
            &reinterpret_cast<unsigned short*>(C)[((size_t)((b * NHEAD + h) * HDIM + d)) * SEQ + s0p]) = pk;
      } else if (mode == 0) {
#pragma unroll
        for (int r = 0; r < 4; ++r) {
          int row = rowb + r;
          float v = (acc[m][n][r] + bv) * oscale;
          int b = row >> 11, s = row & (SEQ - 1), h = col >> 6, d = col & 63;
          reinterpret_cast<unsigned short*>(C)[((size_t)((b * NHEAD + h) * SEQ + s) << 6) + d] = f2bf(v);
        }
      } else {
#pragma unroll
        for (int r = 0; r < 4; ++r)
          reinterpret_cast<float*>(C)[(size_t)(rowb + r) * EMBED + col] = acc[m][n][r] + bv;
      }
    }
  }
}

// fused QKV projection, 1D grid of 768 with XCD-chunked swizzle.
__global__ __launch_bounds__(256) void gemm_qkv(
    const unsigned short* __restrict__ Xq, const unsigned short* __restrict__ Xk,
    const unsigned short* __restrict__ Xv,
    const unsigned short* __restrict__ Wqt, const unsigned short* __restrict__ Wkt,
    const unsigned short* __restrict__ Wvt,
    const float* __restrict__ bq, const float* __restrict__ bk, const float* __restrict__ bv,
    unsigned short* __restrict__ Qb, unsigned short* __restrict__ Kb,
    unsigned short* __restrict__ Vtb, float qscale) {
  const int id = blockIdx.x;
  const int lg = (id & 7) * 96 + (id >> 3);  // bijective: 768 = 8*96
  const int z = lg >> 8, rem = lg & 255;
  const int m0 = (rem >> 3) * 128, n0 = (rem & 7) * 128;
  switch (z) {
    case 0: gemm_core<128>(Xq, Wqt, bq, Qb, qscale, 0, m0, n0); break;
    case 1: gemm_core<128>(Xk, Wkt, bk, Kb, 1.0f, 0, m0, n0); break;
    default: gemm_core<128>(Xv, Wvt, bv, Vtb, 1.0f, 2, m0, n0); break;
  }
}

// output GEMM: 128x64 tiles, 1D grid of 512, XCD-chunked.
__global__ __launch_bounds__(256) void gemm_out(const unsigned short* __restrict__ A,
                                                const unsigned short* __restrict__ Bt,
                                                const float* __restrict__ bias,
                                                float* __restrict__ C) {
  const int id = blockIdx.x;
  const int lg = (id & 7) * 64 + (id >> 3);  // bijective: 512 = 8*64
  const int m0 = (lg >> 4) * 128, n0 = (lg & 15) * 64;
  gemm_core<64>(A, Bt, bias, C, 1.0f, 1, m0, n0);
}

// ---- flash attention, 32x32x16 MFMA ----
// Q,K bf16 [B*H][S][D] (Q pre-scaled by log2e/8); Vt bf16 [B*H][D][S_perm].
// 2 waves x 32 q-rows per block. Lane: ql=lane&31 (q), t=lane>>5.
// QK: sc[kb] = mfma_32x32x16(Kfrag, Qfrag) -> C[k][q]: col q=ql, row
//   k=(reg&3)+8*(reg>>2)+4t within kb*32. [guide-verified C/D layout]
// Softmax in-lane (max3 tree); ONE __shfl_xor(32) per tile (max merge).
// lrow LANE-LOCAL per tile; single cross-half shfl merge in the epilogue.
// PV: A=P from own regs (V^T's bit-swapped seq layout compensates).
// r18: half-tile interleave -- exp2/cvt_pk/PV of sc0 issue before exp2 of
// sc1, so the matrix pipe crunches PV s=0,1 while VALU runs sc1's softmax.
// Staging: r9-verified gload_lds prefetch dbuf + 1 full-drain barrier/tile.
__global__ __launch_bounds__(128) void attn(const unsigned short* __restrict__ Q,
                                            const unsigned short* __restrict__ Kk,
                                            const unsigned short* __restrict__ Vt,
                                            unsigned short* __restrict__ AO) {
  __shared__ __align__(16) unsigned short Klds[2][64 * 64];
  __shared__ __align__(16) unsigned short Vlds[2][64 * 64];  // [d][k_perm]
  const int tid = threadIdx.x, lane = tid & 63, w = tid >> 6;  // w in {0,1}
  const int ql = lane & 31, t = lane >> 5;

  // XCD swizzle: all 32 q-blocks of a head on one XCD (round-robin lin%8).
  const int lin = blockIdx.x;
  const int head = (lin & 7) * 4 + ((lin >> 3) & 3);
  const int q0 = (lin >> 5) * 64;
  const size_t hb = (size_t)head * SEQ * HDIM;
  const unsigned short* Qh = Q + hb;
  const char* KhB = (const char*)(Kk + hb);
  const char* VhB = (const char*)(Vt + hb);  // rows d, 4096B each

  // staging addressing (both-sides swizzle, rule #21)
  const int gsc = ((lane & 7) * 16) ^ ((lane >> 3) << 4);
  const int row0 = w * 32 + (lane >> 3);  // +i*8, i=0..3 -> 32 rows/wave

#define STAGE(kt_, b_)                                                                     \
  {                                                                                        \
    char* kb_ = (char*)Klds[b_];                                                           \
    char* vb_ = (char*)Vlds[b_];                                                           \
    _Pragma("unroll") for (int i_ = 0; i_ < 4; ++i_) {                                     \
      gload16(KhB + (size_t)((kt_)*64 + row0 + i_ * 8) * 128 + gsc,                        \
              kb_ + w * 4096 + i_ * 1024);                                                 \
      gload16(VhB + (size_t)(row0 + i_ * 8) * (SEQ * 2) + (kt_)*128 + gsc,                 \
              vb_ + w * 4096 + i_ * 1024);                                                 \
    }                                                                                      \
  }

  // Q fragments (B-operand): lane supplies Q[ql][d = s*16 + t*8 + e]
  bf16x8 qf[4];
  {
    const unsigned short* qp = Qh + (size_t)(q0 + w * 32 + ql) * HDIM + t * 8;
    qf[0] = *reinterpret_cast<const bf16x8*>(qp);
    qf[1] = *reinterpret_cast<const bf16x8*>(qp + 16);
    qf[2] = *reinterpret_cast<const bf16x8*>(qp + 32);
    qf[3] = *reinterpret_cast<const bf16x8*>(qp + 48);
  }
  f32x16 oacc0 = {}, oacc1 = {};  // d-blocks 0..31, 32..63
  float mrow = -1e30f, lrow = 0.f;  // lrow LANE-LOCAL (half-sum); merged at end

  STAGE(0, 0);
  __syncthreads();  // drains vmcnt(0) -> tile 0 staged

  for (int kt = 0; kt < SEQ / 64; ++kt) {
    const int cur = kt & 1;
    const bool more = (kt + 1 < SEQ / 64);
    if (more) STAGE(kt + 1, cur ^ 1);  // async prefetch; drained by tile-end barrier
    char* Kb8 = (char*)Klds[cur];
    char* Vb8 = (char*)Vlds[cur];

    // S^T = K.Q^T (log2 domain): sc0 = keys kb=0 (k 0..31), sc1 = kb=1
    f32x16 sc0 = {}, sc1 = {};
    __builtin_amdgcn_s_setprio(1);
#pragma unroll
    for (int s = 0; s < 4; ++s) {
      bf16x8 kf0 = *reinterpret_cast<const bf16x8*>(Kb8 + swz(ql, s * 32 + t * 16));
      bf16x8 kf1 = *reinterpret_cast<const bf16x8*>(Kb8 + swz(32 + ql, s * 32 + t * 16));
      sc0 = __builtin_amdgcn_mfma_f32_32x32x16_bf16(kf0, qf[s], sc0, 0, 0, 0);
      sc1 = __builtin_amdgcn_mfma_f32_32x32x16_bf16(kf1, qf[s], sc1, 0, 0, 0);
    }
    __builtin_amdgcn_s_setprio(0);

    // in-lane max over 32 scores (max3 tree), cross-half via verified shfl_xor
    float l1[12];
#pragma unroll
    for (int i = 0; i < 5; ++i) l1[i] = max3f(sc0[3 * i], sc0[3 * i + 1], sc0[3 * i + 2]);
#pragma unroll
    for (int i = 0; i < 5; ++i) l1[5 + i] = max3f(sc1[3 * i], sc1[3 * i + 1], sc1[3 * i + 2]);
    l1[10] = sc0[15];
    l1[11] = sc1[15];
    float l2a = max3f(l1[0], l1[1], l1[2]);
    float l2b = max3f(l1[3], l1[4], l1[5]);
    float l2c = max3f(l1[6], l1[7], l1[8]);
    float l2d = max3f(l1[9], l1[10], l1[11]);
    float mt = fmaxf(max3f(l2a, l2b, l2c), l2d);
    mt = fmaxf(mt, __shfl_xor(mt, 32));

    // T13 defer-max: only rescale when some row's max grew past 2^8 headroom
    if (!__all(mt <= mrow + 8.0f)) {
      float mn = fmaxf(mrow, mt);
      float resc = __builtin_amdgcn_exp2f(mrow - mn);
      lrow *= resc;
#pragma unroll
      for (int r = 0; r < 16; ++r) {
        float rq = __shfl(resc, (r & 3) + 8 * (r >> 2) + 4 * t, 64);
        oacc0[r] *= rq;
        oacc1[r] *= rq;
      }
      mrow = mn;
    }

    // ---- half-tile 0 (sc0, PV s=0,1): softmax VALU then PV MFMAs issue early
    float ps0 = 0.f, ps1 = 0.f;
#pragma unroll
    for (int i = 0; i < 16; ++i) sc0[i] = __builtin_amdgcn_exp2f(sc0[i] - mrow);
    {
      int4 pw0, pw1;
      pw0.x = cvtpk_bf16(sc0[0], sc0[1]);
      pw0.y = cvtpk_bf16(sc0[2], sc0[3]);
      pw0.z = cvtpk_bf16(sc0[4], sc0[5]);
      pw0.w = cvtpk_bf16(sc0[6], sc0[7]);
      pw1.x = cvtpk_bf16(sc0[8], sc0[9]);
      pw1.y = cvtpk_bf16(sc0[10], sc0[11]);
      pw1.z = cvtpk_bf16(sc0[12], sc0[13]);
      pw1.w = cvtpk_bf16(sc0[14], sc0[15]);
      bf16x8 pa0 = __builtin_bit_cast(bf16x8, pw0);
      bf16x8 pa1 = __builtin_bit_cast(bf16x8, pw1);
      bf16x8 v00 = *reinterpret_cast<const bf16x8*>(Vb8 + swz(ql, t * 16));
      bf16x8 v01 = *reinterpret_cast<const bf16x8*>(Vb8 + swz(32 + ql, t * 16));
      bf16x8 v10 = *reinterpret_cast<const bf16x8*>(Vb8 + swz(ql, 32 + t * 16));
      bf16x8 v11 = *reinterpret_cast<const bf16x8*>(Vb8 + swz(32 + ql, 32 + t * 16));
      __builtin_amdgcn_s_setprio(1);
      oacc0 = __builtin_amdgcn_mfma_f32_32x32x16_bf16(pa0, v00, oacc0, 0, 0, 0);
      oacc1 = __builtin_amdgcn_mfma_f32_32x32x16_bf16(pa0, v01, oacc1, 0, 0, 0);
      oacc0 = __builtin_amdgcn_mfma_f32_32x32x16_bf16(pa1, v10, oacc0, 0, 0, 0);
      oacc1 = __builtin_amdgcn_mfma_f32_32x32x16_bf16(pa1, v11, oacc1, 0, 0, 0);
      __builtin_amdgcn_s_setprio(0);
    }
#pragma unroll
    for (int i = 0; i < 4; ++i) {
      ps0 += sc0[4 * i + 0] + sc0[4 * i + 1];
      ps1 += sc0[4 * i + 2] + sc0[4 * i + 3];
    }

    // ---- half-tile 1 (sc1, PV s=2,3): overlaps the in-flight PV MFMAs above
    float ps2 = 0.f, ps3 = 0.f;
#pragma unroll
    for (int i = 0; i < 16; ++i) sc1[i] = __builtin_amdgcn_exp2f(sc1[i] - mrow);
    {
      int4 pw2, pw3;
      pw2.x = cvtpk_bf16(sc1[0], sc1[1]);
      pw2.y = cvtpk_bf16(sc1[2], sc1[3]);
      pw2.z = cvtpk_bf16(sc1[4], sc1[5]);
      pw2.w = cvtpk_bf16(sc1[6], sc1[7]);
      pw3.x = cvtpk_bf16(sc1[8], sc1[9]);
      pw3.y = cvtpk_bf16(sc1[10], sc1[11]);
      pw3.z = cvtpk_bf16(sc1[12], sc1[13]);
      pw3.w = cvtpk_bf16(sc1[14], sc1[15]);
      bf16x8 pa2 = __builtin_bit_cast(bf16x8, pw2);
      bf16x8 pa3 = __builtin_bit_cast(bf16x8, pw3);
      bf16x8 v20 = *reinterpret_cast<const bf16x8*>(Vb8 + swz(ql, 64 + t * 16));
      bf16x8 v21 = *reinterpret_cast<const bf16x8*>(Vb8 + swz(32 + ql, 64 + t * 16));
      bf16x8 v30 = *reinterpret_cast<const bf16x8*>(Vb8 + swz(ql, 96 + t * 16));
      bf16x8 v31 = *reinterpret_cast<const bf16x8*>(Vb8 + swz(32 + ql, 96 + t * 16));
      __builtin_amdgcn_s_setprio(1);
      oacc0 = __builtin_amdgcn_mfma_f32_32x32x16_bf16(pa2, v20, oacc0, 0, 0, 0);
      oacc1 = __builtin_amdgcn_mfma_f32_32x32x16_bf16(pa2, v21, oacc1, 0, 0, 0);
      oacc0 = __builtin_amdgcn_mfma_f32_32x32x16_bf16(pa3, v30, oacc0, 0, 0, 0);
      oacc1 = __builtin_amdgcn_mfma_f32_32x32x16_bf16(pa3, v31, oacc1, 0, 0, 0);
      __builtin_amdgcn_s_setprio(0);
    }
#pragma unroll
    for (int i = 0; i < 4; ++i) {
      ps2 += sc1[4 * i + 0] + sc1[4 * i + 1];
      ps3 += sc1[4 * i + 2] + sc1[4 * i + 3];
    }
    lrow += (ps0 + ps1) + (ps2 + ps3);

    __syncthreads();  // all waves done reading cur + prefetch drained (vmcnt 0)
  }
#undef STAGE

  // merge the two half-sums of lrow once
  lrow += __shfl_xor(lrow, 32);

  const int b = head >> 4, hh = head & 15;
#pragma unroll
  for (int r = 0; r < 16; ++r) {
    int qr = (r & 3) + 8 * (r >> 2) + 4 * t;
    float inv = 1.0f / __shfl(lrow, qr, 64);
    int srow = q0 + w * 32 + qr;
    size_t ob = (size_t)(b * SEQ + srow) * EMBED + hh * 64 + ql;
    AO[ob] = f2bf(oacc0[r] * inv);
    AO[ob + 32] = f2bf(oacc1[r] * inv);
  }
}

extern "C" void kernel_launch(void* const* d_in, const int* in_sizes, int n_in,
                              void* d_out, int out_size, void* d_ws, size_t ws_size,
                              hipStream_t stream) {
  const float* q32 = (const float*)d_in[0];
  const float* k32 = (const float*)d_in[1];
  const float* v32 = (const float*)d_in[2];
  const float* Wq = (const float*)d_in[3]; const float* bq = (const float*)d_in[4];
  const float* Wk = (const float*)d_in[5]; const float* bk = (const float*)d_in[6];
  const float* Wv = (const float*)d_in[7]; const float* bv = (const float*)d_in[8];
  const float* Wo = (const float*)d_in[9]; const float* bo = (const float*)d_in[10];
  float* out = (float*)d_out;

  char* ws = (char*)d_ws;
  const size_t MB = 1u << 20;
  unsigned short* Xq  = (unsigned short*)(ws + 0 * MB);
  unsigned short* Xk  = (unsigned short*)(ws + 8 * MB);
  unsigned short* Xv  = (unsigned short*)(ws + 16 * MB);
  unsigned short* Wqt = (unsigned short*)(ws + 24 * MB);
  unsigned short* Wkt = (unsigned short*)(ws + 26 * MB);
  unsigned short* Wvt = (unsigned short*)(ws + 28 * MB);
  unsigned short* Wot = (unsigned short*)(ws + 30 * MB);
  unsigned short* Qb  = (unsigned short*)(ws + 32 * MB);
  unsigned short* Kb  = (unsigned short*)(ws + 40 * MB);
  unsigned short* Vtb = (unsigned short*)(ws + 48 * MB);
  unsigned short* AO  = Xq;  // safe: GEMM-Q (sole Xq reader) completes before attn writes

  prep<<<7168, 256, 0, stream>>>(q32, k32, v32, Xq, Xk, Xv,
                                 Wq, Wk, Wv, Wo, Wqt, Wkt, Wvt, Wot);

  const float qscale = 0.125f * 1.44269504088896340736f;  // (1/sqrt(64)) * log2(e)
  gemm_qkv<<<768, 256, 0, stream>>>(Xq, Xk, Xv, Wqt, Wkt, Wvt, bq, bk, bv,
                                    Qb, Kb, Vtb, qscale);

  attn<<<dim3(SEQ / 64 * 32), 128, 0, stream>>>(Qb, Kb, Vtb, AO);

  gemm_out<<<512, 256, 0, stream>>>(AO, Wot, bo, out);
}